// Round 1
// baseline (160.973 us; speedup 1.0000x reference)
//
#include <hip/hip_runtime.h>
#include <hip/hip_bf16.h>
#include <stdint.h>
#include <math.h>

// Problem dims
#define B_    1024
#define LAT   64
#define FCON  256
#define IN_SZ 320          // LAT + FCON
#define HID   512
#define E_    8
#define GH    64
#define INTER 576          // LAT + HID
#define OUT_SZ 512
#define NTOT  4096         // E_ * 512
#define KI0   10           // IN_SZ/32
#define KI12  18           // INTER/32

typedef __attribute__((ext_vector_type(8))) __bf16 bf16x8;
typedef __attribute__((ext_vector_type(4))) float  f32x4;

__device__ __forceinline__ float elu_f(float x) { return x > 0.f ? x : expf(x) - 1.f; }
__device__ __forceinline__ __bf16 to_bf16(float f) {
    __hip_bfloat16 h = __float2bfloat16(f);
    return *reinterpret_cast<__bf16*>(&h);
}

// ---------------------------------------------------------------------------
// Fragment layout (mfma_f32_16x16x32_bf16 A/B operand, m89-verified):
//   frag(t0,k0)[lane][j] = X[t0 + (lane&15)][k0 + (lane>>4)*8 + j],  j=0..7
// Packed storage: buf[(tile_idx*KI + ki)*64 + lane] : bf16x8 (16 B/lane).
// ---------------------------------------------------------------------------

// ----- fused prep kernel v2 ------------------------------------------------
// Block order: gate FIRST (longest serial chain, overlap it with everything),
// then zcpack, then LDS-transpose wpack. 960 blocks, all resident at once
// (4 blocks/CU at 33.4 KB LDS).
#define PREP_GATE 64                         // 16 rows/block
#define PREP_ZC   (PREP_GATE + 160)          // 224
#define PREP_W0   (PREP_ZC + 8 * KI0 * 2)    // 384
#define PREP_W1   (PREP_W0 + 8 * KI12 * 2)   // 672
#define PREP_W2   (PREP_W1 + 8 * KI12 * 2)   // 960
#define PREP_ALL  PREP_W2

#define WPAD 261                             // 32 x 261 floats, 2-way banks only
#define SMEM_F (32 * WPAD)                   // 8352 floats = 33.4 KB

__device__ __forceinline__ void do_zcpack(
    int bx, const float* __restrict__ z, const float* __restrict__ c,
    bf16x8* __restrict__ Ap0, bf16x8* __restrict__ Ap1, bf16x8* __restrict__ Ap2)
{
    const int wid  = bx * 4 + (threadIdx.x >> 6);
    const int lane = threadIdx.x & 63, q = lane >> 4, r = lane & 15;
    bf16x8 v;
    if (wid < 128) {                       // z fragment: mi in [0,64), ki in {0,1}
        const int mi = wid >> 1, ki = wid & 1;
        const float* src = z + (size_t)(mi * 16 + r) * LAT + ki * 32 + q * 8;
        const f32x4 lo = *(const f32x4*)src, hi = *(const f32x4*)(src + 4);
#pragma unroll
        for (int j = 0; j < 4; j++) { v[j] = to_bf16(lo[j]); v[j + 4] = to_bf16(hi[j]); }
        Ap0[((size_t)mi * KI0  + ki) * 64 + lane] = v;
        Ap1[((size_t)mi * KI12 + ki) * 64 + lane] = v;
        Ap2[((size_t)mi * KI12 + ki) * 64 + lane] = v;
    } else {                               // c fragment: ki in [2,10)
        const int cid = wid - 128;
        const int mi = cid >> 3, ki = 2 + (cid & 7);
        const float* src = c + (size_t)(mi * 16 + r) * FCON + (ki - 2) * 32 + q * 8;
        const f32x4 lo = *(const f32x4*)src, hi = *(const f32x4*)(src + 4);
#pragma unroll
        for (int j = 0; j < 4; j++) { v[j] = to_bf16(lo[j]); v[j + 4] = to_bf16(hi[j]); }
        Ap0[((size_t)mi * KI0 + ki) * 64 + lane] = v;
    }
}

// LDS-transpose weight pack: block = (expert e, k-tile ki, 256-wide o half).
// Phase 1: 8 coalesced f32x4 loads/thread (32k x 256o tile) -> padded LDS.
// Phase 2: each wave emits 4 frags via 8 ds_read_b32 each (2-way banks = free),
//          coalesced dwordx4 stores. Output layout identical to v1 wpack.
__device__ __forceinline__ void do_wpack2(
    int f, const float* __restrict__ w, bf16x8* __restrict__ Wp, int KI,
    float* __restrict__ lds)
{
    const int e = f / (2 * KI), rem = f % (2 * KI);
    const int ki = rem >> 1, ot2 = rem & 1;
    const int K = KI * 32;
    const float* base = w + ((size_t)e * K + ki * 32) * 512 + ot2 * 256;

#pragma unroll
    for (int p = 0; p < 8; ++p) {
        const int idx = p * 256 + threadIdx.x;   // 0..2047
        const int kl = idx >> 6, c4 = idx & 63;  // k-row 0..31, float4 col
        const f32x4 v = *(const f32x4*)(base + (size_t)kl * 512 + c4 * 4);
        float* d = lds + kl * WPAD + c4 * 4;
        d[0] = v[0]; d[1] = v[1]; d[2] = v[2]; d[3] = v[3];
    }
    __syncthreads();

    const int wv = threadIdx.x >> 6, lane = threadIdx.x & 63;
    const int q = lane >> 4, r = lane & 15;
#pragma unroll
    for (int ff = 0; ff < 4; ++ff) {
        const int fo = wv * 4 + ff;              // 0..15 local o-tile
        const int ol = fo * 16 + r;
        bf16x8 v;
#pragma unroll
        for (int j = 0; j < 8; ++j) v[j] = to_bf16(lds[(q * 8 + j) * WPAD + ol]);
        const int ni = e * 32 + ot2 * 16 + fo;
        Wp[((size_t)ni * KI + ki) * 64 + lane] = v;
    }
}

// Gate v2: 16 rows/block, 4 rows/wave (4x reuse of each gw row-load),
// x staged in LDS, unroll-8 for load MLP, shuffle softmax.
__device__ __forceinline__ void do_gate(
    int bx, const float* __restrict__ z, const float* __restrict__ c,
    const float* __restrict__ gw1, const float* __restrict__ gb1,
    const float* __restrict__ gw2, const float* __restrict__ gb2,
    const float* __restrict__ gw3, const float* __restrict__ gb3,
    float* __restrict__ coeff, float* __restrict__ smem)
{
    float* xs = smem;                 // [16][320]
    float* h  = smem + 16 * 320;      // [16][64], wave-private rows
    const int r0 = bx * 16;
    const int wave = threadIdx.x >> 6, lane = threadIdx.x & 63;

    // stage x = [z | c] for 16 rows (coalesced f32x4)
#pragma unroll
    for (int p = 0; p < 5; ++p) {
        const int idx = p * 256 + threadIdx.x;     // 0..1279
        const int row = idx / 80, c4 = idx % 80;   // 80 float4 per row
        const float* src = (c4 < 16)
            ? (z + (size_t)(r0 + row) * LAT  + c4 * 4)
            : (c + (size_t)(r0 + row) * FCON + (c4 - 16) * 4);
        *(f32x4*)(xs + row * 320 + c4 * 4) = *(const f32x4*)src;
    }
    __syncthreads();

    // g1: rows 4*wave..+3, col = lane
    float a0, a1, a2, a3;
    {
        const float b = gb1[lane];
        a0 = b; a1 = b; a2 = b; a3 = b;
        const float* x0 = xs + (wave * 4 + 0) * 320;
        const float* x1 = xs + (wave * 4 + 1) * 320;
        const float* x2 = xs + (wave * 4 + 2) * 320;
        const float* x3 = xs + (wave * 4 + 3) * 320;
#pragma unroll 8
        for (int i = 0; i < IN_SZ; ++i) {
            const float wv = gw1[i * GH + lane];
            a0 = fmaf(x0[i], wv, a0);
            a1 = fmaf(x1[i], wv, a1);
            a2 = fmaf(x2[i], wv, a2);
            a3 = fmaf(x3[i], wv, a3);
        }
        h[(wave * 4 + 0) * GH + lane] = elu_f(a0);
        h[(wave * 4 + 1) * GH + lane] = elu_f(a1);
        h[(wave * 4 + 2) * GH + lane] = elu_f(a2);
        h[(wave * 4 + 3) * GH + lane] = elu_f(a3);
    }
    // h rows are wave-private: in-order ds ops within the wave, no barrier.
    // g2
    {
        const float b = gb2[lane];
        a0 = b; a1 = b; a2 = b; a3 = b;
        const float* h0 = h + (wave * 4 + 0) * GH;
        const float* h1 = h + (wave * 4 + 1) * GH;
        const float* h2 = h + (wave * 4 + 2) * GH;
        const float* h3 = h + (wave * 4 + 3) * GH;
#pragma unroll 8
        for (int i = 0; i < GH; ++i) {
            const float wv = gw2[i * GH + lane];
            a0 = fmaf(h0[i], wv, a0);
            a1 = fmaf(h1[i], wv, a1);
            a2 = fmaf(h2[i], wv, a2);
            a3 = fmaf(h3[i], wv, a3);
        }
        h[(wave * 4 + 0) * GH + lane] = elu_f(a0);
        h[(wave * 4 + 1) * GH + lane] = elu_f(a1);
        h[(wave * 4 + 2) * GH + lane] = elu_f(a2);
        h[(wave * 4 + 3) * GH + lane] = elu_f(a3);
    }
    // g3 + softmax: lanes 0..31 -> (row_local = lane>>3, e = lane&7)
    if (lane < 32) {
        const int rloc = lane >> 3, e = lane & 7;
        const float* hr = h + (wave * 4 + rloc) * GH;
        float lg = gb3[e];
#pragma unroll 8
        for (int i = 0; i < GH; ++i) lg = fmaf(hr[i], gw3[i * E_ + e], lg);
        float mx = lg;
        mx = fmaxf(mx, __shfl_xor(mx, 1, 8));
        mx = fmaxf(mx, __shfl_xor(mx, 2, 8));
        mx = fmaxf(mx, __shfl_xor(mx, 4, 8));
        const float ex = expf(lg - mx);
        float sm = ex;
        sm += __shfl_xor(sm, 1, 8);
        sm += __shfl_xor(sm, 2, 8);
        sm += __shfl_xor(sm, 4, 8);
        coeff[(size_t)(r0 + wave * 4 + rloc) * E_ + e] = ex / sm;
    }
}

__global__ __launch_bounds__(256) void prep_kernel(
    const float* __restrict__ z, const float* __restrict__ c,
    const float* __restrict__ w0, const float* __restrict__ w1,
    const float* __restrict__ w2,
    const float* __restrict__ gw1, const float* __restrict__ gb1,
    const float* __restrict__ gw2, const float* __restrict__ gb2,
    const float* __restrict__ gw3, const float* __restrict__ gb3,
    bf16x8* __restrict__ Ap0, bf16x8* __restrict__ Ap1, bf16x8* __restrict__ Ap2,
    bf16x8* __restrict__ Wp0, bf16x8* __restrict__ Wp1, bf16x8* __restrict__ Wp2,
    float* __restrict__ coeff)
{
    __shared__ float smem[SMEM_F];
    const int bx = blockIdx.x;
    if (bx < PREP_GATE) {
        do_gate(bx, z, c, gw1, gb1, gw2, gb2, gw3, gb3, coeff, smem);
    } else if (bx < PREP_ZC) {
        do_zcpack(bx - PREP_GATE, z, c, Ap0, Ap1, Ap2);
    } else if (bx < PREP_W0) {
        do_wpack2(bx - PREP_ZC, w0, Wp0, KI0, smem);
    } else if (bx < PREP_W1) {
        do_wpack2(bx - PREP_W0, w1, Wp1, KI12, smem);
    } else {
        do_wpack2(bx - PREP_W1, w2, Wp2, KI12, smem);
    }
}

// ---------------------------------------------------------------------------
// Fused layer kernel, v3: K-split x2 for 2x wave count (2 waves/SIMD).
// Block = 512 threads (8 waves); wave w: kh = w&1 owns half the ki range,
// pair p = w>>1 owns m-tiles by*8 + p*2 + {0,1}. Both halves coeff-mix
// in-register (linear in acc); kh=1 partials merge through 8 KB LDS; kh=0
// adds bias term, applies ELU+pack (layers 0,1) or f32 store (layer 2).
// grid (32 o-tiles, 8 m-blocks) = 256 blocks, 2048 waves.
// ---------------------------------------------------------------------------
template<int KI, int FINAL>
__global__ __launch_bounds__(512) void layer_kernel(
    const bf16x8* __restrict__ Ap, const bf16x8* __restrict__ Wp,
    const float* __restrict__ coeff, const float* __restrict__ bias,
    __bf16* __restrict__ ApN, float* __restrict__ fout)
{
    constexpr int KIH = KI / 2;
    __shared__ float sbuf[4][8][64];           // [pair][u*4+v][lane]
    const int lane = threadIdx.x & 63, w = threadIdx.x >> 6;
    const int kh = w & 1, pp = w >> 1;
    const int q = lane >> 4, r = lane & 15;
    const int o0 = blockIdx.x * 16;
    const int nt = blockIdx.x;                 // o-tile index within each expert
    const int mi0 = blockIdx.y * 8 + pp * 2;   // first of this pair's 2 m-tiles

    const bf16x8* aB0 = Ap + ((size_t)(mi0 + 0) * KI + kh * KIH) * 64 + lane;
    const bf16x8* aB1 = Ap + ((size_t)(mi0 + 1) * KI + kh * KIH) * 64 + lane;
    const bf16x8* bB  = Wp + ((size_t)nt * KI + kh * KIH) * 64 + lane;

    f32x4 acc[2][E_];
#pragma unroll
    for (int u = 0; u < 2; u++)
#pragma unroll
        for (int e = 0; e < E_; e++) acc[u][e] = (f32x4){0.f, 0.f, 0.f, 0.f};

#pragma unroll
    for (int ki = 0; ki < KIH; ++ki) {
        const bf16x8 af0 = aB0[(size_t)ki * 64];
        const bf16x8 af1 = aB1[(size_t)ki * 64];
        bf16x8 bf[E_];
#pragma unroll
        for (int e = 0; e < E_; e++)
            bf[e] = bB[((size_t)e * 32 * KI + ki) * 64];
#pragma unroll
        for (int e = 0; e < E_; e++) {
            acc[0][e] = __builtin_amdgcn_mfma_f32_16x16x32_bf16(af0, bf[e], acc[0][e], 0, 0, 0);
            acc[1][e] = __builtin_amdgcn_mfma_f32_16x16x32_bf16(af1, bf[e], acc[1][e], 0, 0, 0);
        }
    }

    // bias only on the kh=0 half (added exactly once per output)
    float be[E_];
#pragma unroll
    for (int e = 0; e < E_; e++)
        be[e] = kh ? 0.f : bias[(size_t)e * 512 + o0 + r];

    // coeff-mix in-register. D layout: col(o)=lane&15, row(m)=q*4+v [m89]
    float s[2][4];
#pragma unroll
    for (int u = 0; u < 2; u++) {
#pragma unroll
        for (int v = 0; v < 4; v++) {
            const int row = (mi0 + u) * 16 + q * 4 + v;
            const float* cr = coeff + (size_t)row * E_;
            const f32x4 clo = *(const f32x4*)cr, chi = *(const f32x4*)(cr + 4);
            float sv = 0.f;
#pragma unroll
            for (int e = 0; e < 4; e++) sv += clo[e] * (acc[u][e][v] + be[e]);
#pragma unroll
            for (int e = 0; e < 4; e++) sv += chi[e] * (acc[u][4 + e][v] + be[4 + e]);
            s[u][v] = sv;
        }
    }

    if (kh) {
#pragma unroll
        for (int u = 0; u < 2; u++)
#pragma unroll
            for (int v = 0; v < 4; v++) sbuf[pp][u * 4 + v][lane] = s[u][v];
    }
    __syncthreads();
    if (!kh) {
#pragma unroll
        for (int u = 0; u < 2; u++) {
            const int mi = mi0 + u;
#pragma unroll
            for (int v = 0; v < 4; v++) {
                const int row = mi * 16 + q * 4 + v;
                const float t = s[u][v] + sbuf[pp][u * 4 + v][lane];
                if (FINAL) {
                    fout[(size_t)row * OUT_SZ + o0 + r] = t;
                } else {
                    const float hh = elu_f(t);
                    const int k  = LAT + o0 + r;           // 64..575
                    const int ki2 = k >> 5, kq2 = (k & 31) >> 3, jb2 = k & 7;
                    ApN[(((size_t)mi * KI12 + ki2) * 64 + kq2 * 16 + (q * 4 + v)) * 8 + jb2] =
                        to_bf16(hh);
                }
            }
        }
    }
}

// ---------------------------------------------------------------------------
static inline size_t align256(size_t x) { return (x + 255) & ~(size_t)255; }

extern "C" void kernel_launch(void* const* d_in, const int* in_sizes, int n_in,
                              void* d_out, int out_size, void* d_ws, size_t ws_size,
                              hipStream_t stream)
{
    const float* z   = (const float*)d_in[0];
    const float* c   = (const float*)d_in[1];
    const float* w0  = (const float*)d_in[2];
    const float* b0  = (const float*)d_in[3];
    const float* w1  = (const float*)d_in[4];
    const float* b1  = (const float*)d_in[5];
    const float* w2  = (const float*)d_in[6];
    const float* b2  = (const float*)d_in[7];
    const float* gw1 = (const float*)d_in[8];
    const float* gb1 = (const float*)d_in[9];
    const float* gw2 = (const float*)d_in[10];
    const float* gb2 = (const float*)d_in[11];
    const float* gw3 = (const float*)d_in[12];
    const float* gb3 = (const float*)d_in[13];
    float* out = (float*)d_out;

    uint8_t* p = (uint8_t*)d_ws;
    bf16x8* Wp0 = (bf16x8*)p; p += align256((size_t)NTOT * IN_SZ * 2);
    bf16x8* Wp1 = (bf16x8*)p; p += align256((size_t)NTOT * INTER * 2);
    bf16x8* Wp2 = (bf16x8*)p; p += align256((size_t)NTOT * INTER * 2);
    bf16x8* Ap0 = (bf16x8*)p; p += align256((size_t)B_ * IN_SZ * 2);
    bf16x8* Ap1 = (bf16x8*)p; p += align256((size_t)B_ * INTER * 2);
    bf16x8* Ap2 = (bf16x8*)p; p += align256((size_t)B_ * INTER * 2);
    float* coeff = (float*)p; p += align256((size_t)B_ * E_ * 4);

    // 1) fused prep v2: gate first (overlaps), zc-pack, LDS-transpose w-pack
    prep_kernel<<<PREP_ALL, 256, 0, stream>>>(
        z, c, w0, w1, w2, gw1, gb1, gw2, gb2, gw3, gb3,
        Ap0, Ap1, Ap2, Wp0, Wp1, Wp2, coeff);

    // 2) three fused GEMM+reduce layers, K-split x2 (2048 waves each)
    layer_kernel<KI0, 0><<<dim3(32, 8), 512, 0, stream>>>(
        Ap0, Wp0, coeff, b0, (__bf16*)Ap1, nullptr);
    layer_kernel<KI12, 0><<<dim3(32, 8), 512, 0, stream>>>(
        Ap1, Wp1, coeff, b1, (__bf16*)Ap2, nullptr);
    layer_kernel<KI12, 1><<<dim3(32, 8), 512, 0, stream>>>(
        Ap2, Wp2, coeff, b2, nullptr, out);
}

// Round 2
// 137.684 us; speedup vs baseline: 1.1692x; 1.1692x over previous
//
#include <hip/hip_runtime.h>
#include <hip/hip_bf16.h>
#include <stdint.h>
#include <math.h>

// Problem dims
#define B_    1024
#define LAT   64
#define FCON  256
#define IN_SZ 320          // LAT + FCON
#define HID   512
#define E_    8
#define GH    64
#define INTER 576          // LAT + HID
#define OUT_SZ 512
#define NTOT  4096         // E_ * 512
#define KI0   10           // IN_SZ/32
#define KI12  18           // INTER/32

typedef __attribute__((ext_vector_type(8))) __bf16 bf16x8;
typedef __attribute__((ext_vector_type(4))) float  f32x4;

__device__ __forceinline__ float elu_f(float x) { return x > 0.f ? x : expf(x) - 1.f; }
__device__ __forceinline__ __bf16 to_bf16(float f) {
    __hip_bfloat16 h = __float2bfloat16(f);
    return *reinterpret_cast<__bf16*>(&h);
}

// async 16B global -> LDS (dest = wave-uniform base + lane*16)
__device__ __forceinline__ void async_ld16(const void* g, void* l) {
    __builtin_amdgcn_global_load_lds(
        (const __attribute__((address_space(1))) unsigned int*)g,
        (__attribute__((address_space(3))) unsigned int*)l,
        16, 0, 0);
}

// ---------------------------------------------------------------------------
// Fragment layout (mfma_f32_16x16x32_bf16 A/B operand, m89-verified):
//   frag(t0,k0)[lane][j] = X[t0 + (lane&15)][k0 + (lane>>4)*8 + j],  j=0..7
// Packed storage: buf[(tile_idx*KI + ki)*64 + lane] : bf16x8 (16 B/lane).
// ---------------------------------------------------------------------------

// ----- fused prep kernel v2 (UNCHANGED from round 1) -----------------------
#define PREP_GATE 64                         // 16 rows/block
#define PREP_ZC   (PREP_GATE + 160)          // 224
#define PREP_W0   (PREP_ZC + 8 * KI0 * 2)    // 384
#define PREP_W1   (PREP_W0 + 8 * KI12 * 2)   // 672
#define PREP_W2   (PREP_W1 + 8 * KI12 * 2)   // 960
#define PREP_ALL  PREP_W2

#define WPAD 261                             // 32 x 261 floats, 2-way banks only
#define SMEM_F (32 * WPAD)                   // 8352 floats = 33.4 KB

__device__ __forceinline__ void do_zcpack(
    int bx, const float* __restrict__ z, const float* __restrict__ c,
    bf16x8* __restrict__ Ap0, bf16x8* __restrict__ Ap1, bf16x8* __restrict__ Ap2)
{
    const int wid  = bx * 4 + (threadIdx.x >> 6);
    const int lane = threadIdx.x & 63, q = lane >> 4, r = lane & 15;
    bf16x8 v;
    if (wid < 128) {                       // z fragment: mi in [0,64), ki in {0,1}
        const int mi = wid >> 1, ki = wid & 1;
        const float* src = z + (size_t)(mi * 16 + r) * LAT + ki * 32 + q * 8;
        const f32x4 lo = *(const f32x4*)src, hi = *(const f32x4*)(src + 4);
#pragma unroll
        for (int j = 0; j < 4; j++) { v[j] = to_bf16(lo[j]); v[j + 4] = to_bf16(hi[j]); }
        Ap0[((size_t)mi * KI0  + ki) * 64 + lane] = v;
        Ap1[((size_t)mi * KI12 + ki) * 64 + lane] = v;
        Ap2[((size_t)mi * KI12 + ki) * 64 + lane] = v;
    } else {                               // c fragment: ki in [2,10)
        const int cid = wid - 128;
        const int mi = cid >> 3, ki = 2 + (cid & 7);
        const float* src = c + (size_t)(mi * 16 + r) * FCON + (ki - 2) * 32 + q * 8;
        const f32x4 lo = *(const f32x4*)src, hi = *(const f32x4*)(src + 4);
#pragma unroll
        for (int j = 0; j < 4; j++) { v[j] = to_bf16(lo[j]); v[j + 4] = to_bf16(hi[j]); }
        Ap0[((size_t)mi * KI0 + ki) * 64 + lane] = v;
    }
}

__device__ __forceinline__ void do_wpack2(
    int f, const float* __restrict__ w, bf16x8* __restrict__ Wp, int KI,
    float* __restrict__ lds)
{
    const int e = f / (2 * KI), rem = f % (2 * KI);
    const int ki = rem >> 1, ot2 = rem & 1;
    const int K = KI * 32;
    const float* base = w + ((size_t)e * K + ki * 32) * 512 + ot2 * 256;

#pragma unroll
    for (int p = 0; p < 8; ++p) {
        const int idx = p * 256 + threadIdx.x;   // 0..2047
        const int kl = idx >> 6, c4 = idx & 63;  // k-row 0..31, float4 col
        const f32x4 v = *(const f32x4*)(base + (size_t)kl * 512 + c4 * 4);
        float* d = lds + kl * WPAD + c4 * 4;
        d[0] = v[0]; d[1] = v[1]; d[2] = v[2]; d[3] = v[3];
    }
    __syncthreads();

    const int wv = threadIdx.x >> 6, lane = threadIdx.x & 63;
    const int q = lane >> 4, r = lane & 15;
#pragma unroll
    for (int ff = 0; ff < 4; ++ff) {
        const int fo = wv * 4 + ff;              // 0..15 local o-tile
        const int ol = fo * 16 + r;
        bf16x8 v;
#pragma unroll
        for (int j = 0; j < 8; ++j) v[j] = to_bf16(lds[(q * 8 + j) * WPAD + ol]);
        const int ni = e * 32 + ot2 * 16 + fo;
        Wp[((size_t)ni * KI + ki) * 64 + lane] = v;
    }
}

__device__ __forceinline__ void do_gate(
    int bx, const float* __restrict__ z, const float* __restrict__ c,
    const float* __restrict__ gw1, const float* __restrict__ gb1,
    const float* __restrict__ gw2, const float* __restrict__ gb2,
    const float* __restrict__ gw3, const float* __restrict__ gb3,
    float* __restrict__ coeff, float* __restrict__ smem)
{
    float* xs = smem;                 // [16][320]
    float* h  = smem + 16 * 320;      // [16][64], wave-private rows
    const int r0 = bx * 16;
    const int wave = threadIdx.x >> 6, lane = threadIdx.x & 63;

#pragma unroll
    for (int p = 0; p < 5; ++p) {
        const int idx = p * 256 + threadIdx.x;     // 0..1279
        const int row = idx / 80, c4 = idx % 80;   // 80 float4 per row
        const float* src = (c4 < 16)
            ? (z + (size_t)(r0 + row) * LAT  + c4 * 4)
            : (c + (size_t)(r0 + row) * FCON + (c4 - 16) * 4);
        *(f32x4*)(xs + row * 320 + c4 * 4) = *(const f32x4*)src;
    }
    __syncthreads();

    float a0, a1, a2, a3;
    {
        const float b = gb1[lane];
        a0 = b; a1 = b; a2 = b; a3 = b;
        const float* x0 = xs + (wave * 4 + 0) * 320;
        const float* x1 = xs + (wave * 4 + 1) * 320;
        const float* x2 = xs + (wave * 4 + 2) * 320;
        const float* x3 = xs + (wave * 4 + 3) * 320;
#pragma unroll 8
        for (int i = 0; i < IN_SZ; ++i) {
            const float wv = gw1[i * GH + lane];
            a0 = fmaf(x0[i], wv, a0);
            a1 = fmaf(x1[i], wv, a1);
            a2 = fmaf(x2[i], wv, a2);
            a3 = fmaf(x3[i], wv, a3);
        }
        h[(wave * 4 + 0) * GH + lane] = elu_f(a0);
        h[(wave * 4 + 1) * GH + lane] = elu_f(a1);
        h[(wave * 4 + 2) * GH + lane] = elu_f(a2);
        h[(wave * 4 + 3) * GH + lane] = elu_f(a3);
    }
    {
        const float b = gb2[lane];
        a0 = b; a1 = b; a2 = b; a3 = b;
        const float* h0 = h + (wave * 4 + 0) * GH;
        const float* h1 = h + (wave * 4 + 1) * GH;
        const float* h2 = h + (wave * 4 + 2) * GH;
        const float* h3 = h + (wave * 4 + 3) * GH;
#pragma unroll 8
        for (int i = 0; i < GH; ++i) {
            const float wv = gw2[i * GH + lane];
            a0 = fmaf(h0[i], wv, a0);
            a1 = fmaf(h1[i], wv, a1);
            a2 = fmaf(h2[i], wv, a2);
            a3 = fmaf(h3[i], wv, a3);
        }
        h[(wave * 4 + 0) * GH + lane] = elu_f(a0);
        h[(wave * 4 + 1) * GH + lane] = elu_f(a1);
        h[(wave * 4 + 2) * GH + lane] = elu_f(a2);
        h[(wave * 4 + 3) * GH + lane] = elu_f(a3);
    }
    if (lane < 32) {
        const int rloc = lane >> 3, e = lane & 7;
        const float* hr = h + (wave * 4 + rloc) * GH;
        float lg = gb3[e];
#pragma unroll 8
        for (int i = 0; i < GH; ++i) lg = fmaf(hr[i], gw3[i * E_ + e], lg);
        float mx = lg;
        mx = fmaxf(mx, __shfl_xor(mx, 1, 8));
        mx = fmaxf(mx, __shfl_xor(mx, 2, 8));
        mx = fmaxf(mx, __shfl_xor(mx, 4, 8));
        const float ex = expf(lg - mx);
        float sm = ex;
        sm += __shfl_xor(sm, 1, 8);
        sm += __shfl_xor(sm, 2, 8);
        sm += __shfl_xor(sm, 4, 8);
        coeff[(size_t)(r0 + wave * 4 + rloc) * E_ + e] = ex / sm;
    }
}

__global__ __launch_bounds__(256) void prep_kernel(
    const float* __restrict__ z, const float* __restrict__ c,
    const float* __restrict__ w0, const float* __restrict__ w1,
    const float* __restrict__ w2,
    const float* __restrict__ gw1, const float* __restrict__ gb1,
    const float* __restrict__ gw2, const float* __restrict__ gb2,
    const float* __restrict__ gw3, const float* __restrict__ gb3,
    bf16x8* __restrict__ Ap0, bf16x8* __restrict__ Ap1, bf16x8* __restrict__ Ap2,
    bf16x8* __restrict__ Wp0, bf16x8* __restrict__ Wp1, bf16x8* __restrict__ Wp2,
    float* __restrict__ coeff)
{
    __shared__ float smem[SMEM_F];
    const int bx = blockIdx.x;
    if (bx < PREP_GATE) {
        do_gate(bx, z, c, gw1, gb1, gw2, gb2, gw3, gb3, coeff, smem);
    } else if (bx < PREP_ZC) {
        do_zcpack(bx - PREP_GATE, z, c, Ap0, Ap1, Ap2);
    } else if (bx < PREP_W0) {
        do_wpack2(bx - PREP_ZC, w0, Wp0, KI0, smem);
    } else if (bx < PREP_W1) {
        do_wpack2(bx - PREP_W0, w1, Wp1, KI12, smem);
    } else {
        do_wpack2(bx - PREP_W1, w2, Wp2, KI12, smem);
    }
}

// ---------------------------------------------------------------------------
// Fused layer kernel v4: LDS-staged B via global_load_lds, double-buffered,
// 2-phase pipeline (T3 minimum template). Block = 256 thr (4 waves), each
// wave owns 1 m-tile (acc[E] = 32 VGPR). B frags staged ONCE per block per
// K-chunk (CHUNK=2 ki, 16 KB) and shared by all 4 waves via ds_read_b128;
// A frags register-prefetched 1 step ahead. Stage for step s+1 is issued
// BEFORE step s compute -> latency hides under 16 MFMA + 16 ds_read; the
// __syncthreads (vmcnt drain) per step closes the pipeline. grid (32,16) =
// 512 blocks = 2 blocks/CU for inter-block overlap of barrier drains.
// ---------------------------------------------------------------------------
template<int KI, int FINAL>
__global__ __launch_bounds__(256) void layer_kernel(
    const bf16x8* __restrict__ Ap, const bf16x8* __restrict__ Wp,
    const float* __restrict__ coeff, const float* __restrict__ bias,
    __bf16* __restrict__ ApN, float* __restrict__ fout)
{
    constexpr int NS = KI / 2;                 // K-chunks of 2 ki
    __shared__ bf16x8 bs[2][2][E_][64];        // [buf][kk][e][lane] = 32 KB
    const int lane = threadIdx.x & 63, w = threadIdx.x >> 6;
    const int q = lane >> 4, r = lane & 15;
    const int o0 = blockIdx.x * 16;
    const int nt = blockIdx.x;                 // o-tile index within each expert
    const int mi = blockIdx.y * 4 + w;         // this wave's m-tile

    const bf16x8* aB = Ap + (size_t)mi * KI * 64 + lane;
    const int e0 = w * 2;                      // this wave stages experts e0, e0+1

    f32x4 acc[E_];
#pragma unroll
    for (int e = 0; e < E_; e++) acc[e] = (f32x4){0.f, 0.f, 0.f, 0.f};

    // stage K-chunk s into buffer buf: 16 frags, 4 per wave (2 kk x 2 e)
#define STAGE(s_, buf_)                                                        \
    {                                                                          \
        _Pragma("unroll")                                                      \
        for (int kk = 0; kk < 2; ++kk) {                                       \
            _Pragma("unroll")                                                  \
            for (int t = 0; t < 2; ++t) {                                      \
                const int e = e0 + t;                                          \
                const bf16x8* g = Wp +                                         \
                    ((size_t)e * 32 * KI + (size_t)nt * KI + ((s_) * 2 + kk)) * 64 + lane; \
                async_ld16((const void*)g, (void*)&bs[buf_][kk][e][0]);        \
            }                                                                  \
        }                                                                      \
    }

    STAGE(0, 0);
    bf16x8 af0 = aB[0], af1 = aB[64];
    __syncthreads();                           // vmcnt(0) drain + barrier

    int cur = 0;
#pragma unroll
    for (int s = 0; s < NS; ++s) {
        bf16x8 afn0 = af0, afn1 = af1;
        if (s + 1 < NS) {
            STAGE(s + 1, cur ^ 1);             // issue BEFORE compute: hidden
            afn0 = aB[(size_t)(s * 2 + 2) * 64];
            afn1 = aB[(size_t)(s * 2 + 3) * 64];
        }
#pragma unroll
        for (int kk = 0; kk < 2; ++kk) {
            const bf16x8 af = kk ? af1 : af0;
            bf16x8 bfr[E_];
#pragma unroll
            for (int e = 0; e < E_; e++) bfr[e] = bs[cur][kk][e][lane];
#pragma unroll
            for (int e = 0; e < E_; e++)
                acc[e] = __builtin_amdgcn_mfma_f32_16x16x32_bf16(af, bfr[e], acc[e], 0, 0, 0);
        }
        __syncthreads();                       // stage(s+1) complete; reads of cur done
        af0 = afn0; af1 = afn1; cur ^= 1;
    }
#undef STAGE

    // epilogue: s = sum_e coeff[row,e]*(acc[e]+bias[e,o])
    float be[E_];
#pragma unroll
    for (int e = 0; e < E_; e++) be[e] = bias[(size_t)e * 512 + o0 + r];

    // D layout: col(o) = lane&15, row(m) = q*4 + v  [m89-verified]
#pragma unroll
    for (int v = 0; v < 4; v++) {
        const int row = mi * 16 + q * 4 + v;
        const float* cr = coeff + (size_t)row * E_;
        const f32x4 clo = *(const f32x4*)cr, chi = *(const f32x4*)(cr + 4);
        float sv = 0.f;
#pragma unroll
        for (int e = 0; e < 4; e++) sv += clo[e] * (acc[e][v] + be[e]);
#pragma unroll
        for (int e = 0; e < 4; e++) sv += chi[e] * (acc[4 + e][v] + be[4 + e]);
        if (FINAL) {
            fout[(size_t)row * OUT_SZ + o0 + r] = sv;
        } else {
            const float hh = elu_f(sv);
            const int k  = LAT + o0 + r;           // 64..575
            const int ki2 = k >> 5, kq2 = (k & 31) >> 3, jb2 = k & 7;
            ApN[(((size_t)mi * KI12 + ki2) * 64 + kq2 * 16 + (q * 4 + v)) * 8 + jb2] =
                to_bf16(hh);
        }
    }
}

// ---------------------------------------------------------------------------
static inline size_t align256(size_t x) { return (x + 255) & ~(size_t)255; }

extern "C" void kernel_launch(void* const* d_in, const int* in_sizes, int n_in,
                              void* d_out, int out_size, void* d_ws, size_t ws_size,
                              hipStream_t stream)
{
    const float* z   = (const float*)d_in[0];
    const float* c   = (const float*)d_in[1];
    const float* w0  = (const float*)d_in[2];
    const float* b0  = (const float*)d_in[3];
    const float* w1  = (const float*)d_in[4];
    const float* b1  = (const float*)d_in[5];
    const float* w2  = (const float*)d_in[6];
    const float* b2  = (const float*)d_in[7];
    const float* gw1 = (const float*)d_in[8];
    const float* gb1 = (const float*)d_in[9];
    const float* gw2 = (const float*)d_in[10];
    const float* gb2 = (const float*)d_in[11];
    const float* gw3 = (const float*)d_in[12];
    const float* gb3 = (const float*)d_in[13];
    float* out = (float*)d_out;

    uint8_t* p = (uint8_t*)d_ws;
    bf16x8* Wp0 = (bf16x8*)p; p += align256((size_t)NTOT * IN_SZ * 2);
    bf16x8* Wp1 = (bf16x8*)p; p += align256((size_t)NTOT * INTER * 2);
    bf16x8* Wp2 = (bf16x8*)p; p += align256((size_t)NTOT * INTER * 2);
    bf16x8* Ap0 = (bf16x8*)p; p += align256((size_t)B_ * IN_SZ * 2);
    bf16x8* Ap1 = (bf16x8*)p; p += align256((size_t)B_ * INTER * 2);
    bf16x8* Ap2 = (bf16x8*)p; p += align256((size_t)B_ * INTER * 2);
    float* coeff = (float*)p; p += align256((size_t)B_ * E_ * 4);

    // 1) fused prep v2 (unchanged): gate-first, zc-pack, LDS-transpose w-pack
    prep_kernel<<<PREP_ALL, 256, 0, stream>>>(
        z, c, w0, w1, w2, gw1, gb1, gw2, gb2, gw3, gb3,
        Ap0, Ap1, Ap2, Wp0, Wp1, Wp2, coeff);

    // 2) three fused GEMM+reduce layers, LDS-staged B + 2-phase pipeline
    layer_kernel<KI0, 0><<<dim3(32, 16), 256, 0, stream>>>(
        Ap0, Wp0, coeff, b0, (__bf16*)Ap1, nullptr);
    layer_kernel<KI12, 0><<<dim3(32, 16), 256, 0, stream>>>(
        Ap1, Wp1, coeff, b1, (__bf16*)Ap2, nullptr);
    layer_kernel<KI12, 1><<<dim3(32, 16), 256, 0, stream>>>(
        Ap2, Wp2, coeff, b2, nullptr, out);
}

// Round 3
// 136.388 us; speedup vs baseline: 1.1803x; 1.0095x over previous
//
#include <hip/hip_runtime.h>
#include <hip/hip_bf16.h>
#include <stdint.h>
#include <math.h>

// Problem dims
#define B_    1024
#define LAT   64
#define FCON  256
#define IN_SZ 320          // LAT + FCON
#define HID   512
#define E_    8
#define GH    64
#define INTER 576          // LAT + HID
#define OUT_SZ 512
#define NTOT  4096         // E_ * 512
#define KI0   10           // IN_SZ/32
#define KI12  18           // INTER/32

typedef __attribute__((ext_vector_type(8))) __bf16 bf16x8;
typedef __attribute__((ext_vector_type(4))) float  f32x4;

__device__ __forceinline__ float elu_f(float x) { return x > 0.f ? x : expf(x) - 1.f; }
__device__ __forceinline__ __bf16 to_bf16(float f) {
    __hip_bfloat16 h = __float2bfloat16(f);
    return *reinterpret_cast<__bf16*>(&h);
}

// async 16B global -> LDS (dest = wave-uniform base + lane*16)
__device__ __forceinline__ void async_ld16(const void* g, void* l) {
    __builtin_amdgcn_global_load_lds(
        (const __attribute__((address_space(1))) unsigned int*)g,
        (__attribute__((address_space(3))) unsigned int*)l,
        16, 0, 0);
}

// ---------------------------------------------------------------------------
// Fragment layout (mfma_f32_16x16x32_bf16 A/B operand, m89-verified):
//   frag(t0,k0)[lane][j] = X[t0 + (lane&15)][k0 + (lane>>4)*8 + j],  j=0..7
// Packed storage: buf[(tile_idx*KI + ki)*64 + lane] : bf16x8 (16 B/lane).
// ---------------------------------------------------------------------------

// ----- fused prep kernel v2 (UNCHANGED from round 2) -----------------------
#define PREP_GATE 64                         // 16 rows/block
#define PREP_ZC   (PREP_GATE + 160)          // 224
#define PREP_W0   (PREP_ZC + 8 * KI0 * 2)    // 384
#define PREP_W1   (PREP_W0 + 8 * KI12 * 2)   // 672
#define PREP_W2   (PREP_W1 + 8 * KI12 * 2)   // 960
#define PREP_ALL  PREP_W2

#define WPAD 261                             // 32 x 261 floats, 2-way banks only
#define SMEM_F (32 * WPAD)                   // 8352 floats = 33.4 KB

__device__ __forceinline__ void do_zcpack(
    int bx, const float* __restrict__ z, const float* __restrict__ c,
    bf16x8* __restrict__ Ap0, bf16x8* __restrict__ Ap1, bf16x8* __restrict__ Ap2)
{
    const int wid  = bx * 4 + (threadIdx.x >> 6);
    const int lane = threadIdx.x & 63, q = lane >> 4, r = lane & 15;
    bf16x8 v;
    if (wid < 128) {                       // z fragment: mi in [0,64), ki in {0,1}
        const int mi = wid >> 1, ki = wid & 1;
        const float* src = z + (size_t)(mi * 16 + r) * LAT + ki * 32 + q * 8;
        const f32x4 lo = *(const f32x4*)src, hi = *(const f32x4*)(src + 4);
#pragma unroll
        for (int j = 0; j < 4; j++) { v[j] = to_bf16(lo[j]); v[j + 4] = to_bf16(hi[j]); }
        Ap0[((size_t)mi * KI0  + ki) * 64 + lane] = v;
        Ap1[((size_t)mi * KI12 + ki) * 64 + lane] = v;
        Ap2[((size_t)mi * KI12 + ki) * 64 + lane] = v;
    } else {                               // c fragment: ki in [2,10)
        const int cid = wid - 128;
        const int mi = cid >> 3, ki = 2 + (cid & 7);
        const float* src = c + (size_t)(mi * 16 + r) * FCON + (ki - 2) * 32 + q * 8;
        const f32x4 lo = *(const f32x4*)src, hi = *(const f32x4*)(src + 4);
#pragma unroll
        for (int j = 0; j < 4; j++) { v[j] = to_bf16(lo[j]); v[j + 4] = to_bf16(hi[j]); }
        Ap0[((size_t)mi * KI0 + ki) * 64 + lane] = v;
    }
}

__device__ __forceinline__ void do_wpack2(
    int f, const float* __restrict__ w, bf16x8* __restrict__ Wp, int KI,
    float* __restrict__ lds)
{
    const int e = f / (2 * KI), rem = f % (2 * KI);
    const int ki = rem >> 1, ot2 = rem & 1;
    const int K = KI * 32;
    const float* base = w + ((size_t)e * K + ki * 32) * 512 + ot2 * 256;

#pragma unroll
    for (int p = 0; p < 8; ++p) {
        const int idx = p * 256 + threadIdx.x;   // 0..2047
        const int kl = idx >> 6, c4 = idx & 63;  // k-row 0..31, float4 col
        const f32x4 v = *(const f32x4*)(base + (size_t)kl * 512 + c4 * 4);
        float* d = lds + kl * WPAD + c4 * 4;
        d[0] = v[0]; d[1] = v[1]; d[2] = v[2]; d[3] = v[3];
    }
    __syncthreads();

    const int wv = threadIdx.x >> 6, lane = threadIdx.x & 63;
    const int q = lane >> 4, r = lane & 15;
#pragma unroll
    for (int ff = 0; ff < 4; ++ff) {
        const int fo = wv * 4 + ff;              // 0..15 local o-tile
        const int ol = fo * 16 + r;
        bf16x8 v;
#pragma unroll
        for (int j = 0; j < 8; ++j) v[j] = to_bf16(lds[(q * 8 + j) * WPAD + ol]);
        const int ni = e * 32 + ot2 * 16 + fo;
        Wp[((size_t)ni * KI + ki) * 64 + lane] = v;
    }
}

__device__ __forceinline__ void do_gate(
    int bx, const float* __restrict__ z, const float* __restrict__ c,
    const float* __restrict__ gw1, const float* __restrict__ gb1,
    const float* __restrict__ gw2, const float* __restrict__ gb2,
    const float* __restrict__ gw3, const float* __restrict__ gb3,
    float* __restrict__ coeff, float* __restrict__ smem)
{
    float* xs = smem;                 // [16][320]
    float* h  = smem + 16 * 320;      // [16][64], wave-private rows
    const int r0 = bx * 16;
    const int wave = threadIdx.x >> 6, lane = threadIdx.x & 63;

#pragma unroll
    for (int p = 0; p < 5; ++p) {
        const int idx = p * 256 + threadIdx.x;     // 0..1279
        const int row = idx / 80, c4 = idx % 80;   // 80 float4 per row
        const float* src = (c4 < 16)
            ? (z + (size_t)(r0 + row) * LAT  + c4 * 4)
            : (c + (size_t)(r0 + row) * FCON + (c4 - 16) * 4);
        *(f32x4*)(xs + row * 320 + c4 * 4) = *(const f32x4*)src;
    }
    __syncthreads();

    float a0, a1, a2, a3;
    {
        const float b = gb1[lane];
        a0 = b; a1 = b; a2 = b; a3 = b;
        const float* x0 = xs + (wave * 4 + 0) * 320;
        const float* x1 = xs + (wave * 4 + 1) * 320;
        const float* x2 = xs + (wave * 4 + 2) * 320;
        const float* x3 = xs + (wave * 4 + 3) * 320;
#pragma unroll 8
        for (int i = 0; i < IN_SZ; ++i) {
            const float wv = gw1[i * GH + lane];
            a0 = fmaf(x0[i], wv, a0);
            a1 = fmaf(x1[i], wv, a1);
            a2 = fmaf(x2[i], wv, a2);
            a3 = fmaf(x3[i], wv, a3);
        }
        h[(wave * 4 + 0) * GH + lane] = elu_f(a0);
        h[(wave * 4 + 1) * GH + lane] = elu_f(a1);
        h[(wave * 4 + 2) * GH + lane] = elu_f(a2);
        h[(wave * 4 + 3) * GH + lane] = elu_f(a3);
    }
    {
        const float b = gb2[lane];
        a0 = b; a1 = b; a2 = b; a3 = b;
        const float* h0 = h + (wave * 4 + 0) * GH;
        const float* h1 = h + (wave * 4 + 1) * GH;
        const float* h2 = h + (wave * 4 + 2) * GH;
        const float* h3 = h + (wave * 4 + 3) * GH;
#pragma unroll 8
        for (int i = 0; i < GH; ++i) {
            const float wv = gw2[i * GH + lane];
            a0 = fmaf(h0[i], wv, a0);
            a1 = fmaf(h1[i], wv, a1);
            a2 = fmaf(h2[i], wv, a2);
            a3 = fmaf(h3[i], wv, a3);
        }
        h[(wave * 4 + 0) * GH + lane] = elu_f(a0);
        h[(wave * 4 + 1) * GH + lane] = elu_f(a1);
        h[(wave * 4 + 2) * GH + lane] = elu_f(a2);
        h[(wave * 4 + 3) * GH + lane] = elu_f(a3);
    }
    if (lane < 32) {
        const int rloc = lane >> 3, e = lane & 7;
        const float* hr = h + (wave * 4 + rloc) * GH;
        float lg = gb3[e];
#pragma unroll 8
        for (int i = 0; i < GH; ++i) lg = fmaf(hr[i], gw3[i * E_ + e], lg);
        float mx = lg;
        mx = fmaxf(mx, __shfl_xor(mx, 1, 8));
        mx = fmaxf(mx, __shfl_xor(mx, 2, 8));
        mx = fmaxf(mx, __shfl_xor(mx, 4, 8));
        const float ex = expf(lg - mx);
        float sm = ex;
        sm += __shfl_xor(sm, 1, 8);
        sm += __shfl_xor(sm, 2, 8);
        sm += __shfl_xor(sm, 4, 8);
        coeff[(size_t)(r0 + wave * 4 + rloc) * E_ + e] = ex / sm;
    }
}

__global__ __launch_bounds__(256) void prep_kernel(
    const float* __restrict__ z, const float* __restrict__ c,
    const float* __restrict__ w0, const float* __restrict__ w1,
    const float* __restrict__ w2,
    const float* __restrict__ gw1, const float* __restrict__ gb1,
    const float* __restrict__ gw2, const float* __restrict__ gb2,
    const float* __restrict__ gw3, const float* __restrict__ gb3,
    bf16x8* __restrict__ Ap0, bf16x8* __restrict__ Ap1, bf16x8* __restrict__ Ap2,
    bf16x8* __restrict__ Wp0, bf16x8* __restrict__ Wp1, bf16x8* __restrict__ Wp2,
    float* __restrict__ coeff)
{
    __shared__ float smem[SMEM_F];
    const int bx = blockIdx.x;
    if (bx < PREP_GATE) {
        do_gate(bx, z, c, gw1, gb1, gw2, gb2, gw3, gb3, coeff, smem);
    } else if (bx < PREP_ZC) {
        do_zcpack(bx - PREP_GATE, z, c, Ap0, Ap1, Ap2);
    } else if (bx < PREP_W0) {
        do_wpack2(bx - PREP_ZC, w0, Wp0, KI0, smem);
    } else if (bx < PREP_W1) {
        do_wpack2(bx - PREP_W0, w1, Wp1, KI12, smem);
    } else {
        do_wpack2(bx - PREP_W1, w2, Wp2, KI12, smem);
    }
}

// ---------------------------------------------------------------------------
// Fused layer kernel v5: counted-vmcnt 2-barrier pipeline (T3+T4).
// Same geometry as v4 (4 waves, 1 m-tile/wave, 16 B-frags/chunk in dbuf LDS)
// but replaces __syncthreads (full vmcnt(0) drain) with:
//   issue stage(s+1)+A(s+1)  [exactly 6 VMEM ops/wave]
//   s_waitcnt vmcnt(6)       <- waits chunk s only, keeps 6 ops in flight
//   s_barrier ; ds_read+MFMA ; sched_barrier ; s_barrier
// Correctness: barrier2 of step s-1 orders all reads of buf[x^1] before any
// stage(s+1) write into it; all ds_reads are consumed by MFMAs (compiler
// lgkmcnt) before barrier2; vmcnt(6) leaves only the 6 newest ops in flight,
// so chunk s's stage + A(s) regs are complete at barrier1.
// ---------------------------------------------------------------------------
template<int KI, int FINAL>
__global__ __launch_bounds__(256) void layer_kernel(
    const bf16x8* __restrict__ Ap, const bf16x8* __restrict__ Wp,
    const float* __restrict__ coeff, const float* __restrict__ bias,
    __bf16* __restrict__ ApN, float* __restrict__ fout)
{
    constexpr int NS = KI / 2;                 // K-chunks of 2 ki
    __shared__ bf16x8 bs[2][2][E_][64];        // [buf][kk][e][lane] = 32 KB
    const int lane = threadIdx.x & 63, w = threadIdx.x >> 6;
    const int q = lane >> 4, r = lane & 15;
    const int o0 = blockIdx.x * 16;
    const int nt = blockIdx.x;                 // o-tile index within each expert
    const int mi = blockIdx.y * 4 + w;         // this wave's m-tile

    const bf16x8* aB = Ap + (size_t)mi * KI * 64 + lane;
    const int e0 = w * 2;                      // this wave stages experts e0, e0+1

    f32x4 acc[E_];
#pragma unroll
    for (int e = 0; e < E_; e++) acc[e] = (f32x4){0.f, 0.f, 0.f, 0.f};

    // stage K-chunk s into buffer buf: 16 frags, 4 per wave (2 kk x 2 e)
#define STAGE(s_, buf_)                                                        \
    {                                                                          \
        _Pragma("unroll")                                                      \
        for (int kk = 0; kk < 2; ++kk) {                                       \
            _Pragma("unroll")                                                  \
            for (int t = 0; t < 2; ++t) {                                      \
                const int e = e0 + t;                                          \
                const bf16x8* g = Wp +                                         \
                    ((size_t)e * 32 * KI + (size_t)nt * KI + ((s_) * 2 + kk)) * 64 + lane; \
                async_ld16((const void*)g, (void*)&bs[buf_][kk][e][0]);        \
            }                                                                  \
        }                                                                      \
    }

    STAGE(0, 0);                               // 4 VMEM
    bf16x8 af0 = aB[0], af1 = aB[64];          // 2 VMEM  (A chunk 0)

    int cur = 0;
#pragma unroll
    for (int s = 0; s < NS; ++s) {
        bf16x8 afn0 = af0, afn1 = af1;
        if (s + 1 < NS) {
            STAGE(s + 1, cur ^ 1);             // 4 VMEM into other buffer
            afn0 = aB[(size_t)(s * 2 + 2) * 64];   // 2 VMEM (A chunk s+1)
            afn1 = aB[(size_t)(s * 2 + 3) * 64];
            // keep the 6 newest (chunk s+1) in flight; chunk s is complete
            asm volatile("s_waitcnt vmcnt(6)" ::: "memory");
        } else {
            asm volatile("s_waitcnt vmcnt(0)" ::: "memory");
        }
        __builtin_amdgcn_s_barrier();          // buf[cur] ready for all waves
        __builtin_amdgcn_sched_barrier(0);

#pragma unroll
        for (int kk = 0; kk < 2; ++kk) {
            const bf16x8 af = kk ? af1 : af0;
            bf16x8 bfr[E_];
#pragma unroll
            for (int e = 0; e < E_; e++) bfr[e] = bs[cur][kk][e][lane];
#pragma unroll
            for (int e = 0; e < E_; e++)
                acc[e] = __builtin_amdgcn_mfma_f32_16x16x32_bf16(af, bfr[e], acc[e], 0, 0, 0);
        }

        __builtin_amdgcn_sched_barrier(0);
        __builtin_amdgcn_s_barrier();          // all reads of buf[cur] done
        af0 = afn0; af1 = afn1; cur ^= 1;
    }
#undef STAGE

    // epilogue: s = sum_e coeff[row,e]*(acc[e]+bias[e,o])
    float be[E_];
#pragma unroll
    for (int e = 0; e < E_; e++) be[e] = bias[(size_t)e * 512 + o0 + r];

    // D layout: col(o) = lane&15, row(m) = q*4 + v  [m89-verified]
#pragma unroll
    for (int v = 0; v < 4; v++) {
        const int row = mi * 16 + q * 4 + v;
        const float* cr = coeff + (size_t)row * E_;
        const f32x4 clo = *(const f32x4*)cr, chi = *(const f32x4*)(cr + 4);
        float sv = 0.f;
#pragma unroll
        for (int e = 0; e < 4; e++) sv += clo[e] * (acc[e][v] + be[e]);
#pragma unroll
        for (int e = 0; e < 4; e++) sv += chi[e] * (acc[4 + e][v] + be[4 + e]);
        if (FINAL) {
            fout[(size_t)row * OUT_SZ + o0 + r] = sv;
        } else {
            const float hh = elu_f(sv);
            const int k  = LAT + o0 + r;           // 64..575
            const int ki2 = k >> 5, kq2 = (k & 31) >> 3, jb2 = k & 7;
            ApN[(((size_t)mi * KI12 + ki2) * 64 + kq2 * 16 + (q * 4 + v)) * 8 + jb2] =
                to_bf16(hh);
        }
    }
}

// ---------------------------------------------------------------------------
static inline size_t align256(size_t x) { return (x + 255) & ~(size_t)255; }

extern "C" void kernel_launch(void* const* d_in, const int* in_sizes, int n_in,
                              void* d_out, int out_size, void* d_ws, size_t ws_size,
                              hipStream_t stream)
{
    const float* z   = (const float*)d_in[0];
    const float* c   = (const float*)d_in[1];
    const float* w0  = (const float*)d_in[2];
    const float* b0  = (const float*)d_in[3];
    const float* w1  = (const float*)d_in[4];
    const float* b1  = (const float*)d_in[5];
    const float* w2  = (const float*)d_in[6];
    const float* b2  = (const float*)d_in[7];
    const float* gw1 = (const float*)d_in[8];
    const float* gb1 = (const float*)d_in[9];
    const float* gw2 = (const float*)d_in[10];
    const float* gb2 = (const float*)d_in[11];
    const float* gw3 = (const float*)d_in[12];
    const float* gb3 = (const float*)d_in[13];
    float* out = (float*)d_out;

    uint8_t* p = (uint8_t*)d_ws;
    bf16x8* Wp0 = (bf16x8*)p; p += align256((size_t)NTOT * IN_SZ * 2);
    bf16x8* Wp1 = (bf16x8*)p; p += align256((size_t)NTOT * INTER * 2);
    bf16x8* Wp2 = (bf16x8*)p; p += align256((size_t)NTOT * INTER * 2);
    bf16x8* Ap0 = (bf16x8*)p; p += align256((size_t)B_ * IN_SZ * 2);
    bf16x8* Ap1 = (bf16x8*)p; p += align256((size_t)B_ * INTER * 2);
    bf16x8* Ap2 = (bf16x8*)p; p += align256((size_t)B_ * INTER * 2);
    float* coeff = (float*)p; p += align256((size_t)B_ * E_ * 4);

    // 1) fused prep v2 (unchanged): gate-first, zc-pack, LDS-transpose w-pack
    prep_kernel<<<PREP_ALL, 256, 0, stream>>>(
        z, c, w0, w1, w2, gw1, gb1, gw2, gb2, gw3, gb3,
        Ap0, Ap1, Ap2, Wp0, Wp1, Wp2, coeff);

    // 2) three fused GEMM+reduce layers, counted-vmcnt pipeline (T3+T4)
    layer_kernel<KI0, 0><<<dim3(32, 16), 256, 0, stream>>>(
        Ap0, Wp0, coeff, b0, (__bf16*)Ap1, nullptr);
    layer_kernel<KI12, 0><<<dim3(32, 16), 256, 0, stream>>>(
        Ap1, Wp1, coeff, b1, (__bf16*)Ap2, nullptr);
    layer_kernel<KI12, 1><<<dim3(32, 16), 256, 0, stream>>>(
        Ap2, Wp2, coeff, b2, nullptr, out);
}